// Round 11
// baseline (209.082 us; speedup 1.0000x reference)
//
#include <hip/hip_runtime.h>

typedef unsigned short u16;
typedef unsigned int   u32;
typedef __attribute__((ext_vector_type(8))) short bf16x8;
typedef __attribute__((ext_vector_type(4))) float f32x4;

#define SEQ 1024
#define BSZ 8
#define EMB 1024
#define NH  16
#define DH  64
#define KVB 64
#define L2E 1.44269504088896f

__device__ __forceinline__ u16 f2bf(float f) {
    u32 u = __float_as_uint(f);
    u32 r = u + 0x7FFFu + ((u >> 16) & 1u);   // round-to-nearest-even
    return (u16)(r >> 16);
}
__device__ __forceinline__ float bf2f(u16 u) {
    return __uint_as_float((u32)u << 16);
}
__device__ __forceinline__ float fexp2(float x) {
    return __builtin_amdgcn_exp2f(x);
}

#define GLDS16(g, l) __builtin_amdgcn_global_load_lds( \
    (const __attribute__((address_space(1))) void*)(g), \
    (__attribute__((address_space(3))) void*)(l), 16, 0, 0)

// ------- merged convert: x (fp32)->xb (bf16); w (K,N) fp32 -> wT (N,K) bf16 -------
__global__ __launch_bounds__(256) void cvt_k(
    const float* __restrict__ x, const float* __restrict__ w0,
    const float* __restrict__ w1, const float* __restrict__ w2,
    const float* __restrict__ w3, u16* __restrict__ xb, u16* __restrict__ wT)
{
    const int bid = blockIdx.x;
    if (bid < 4096) {
        size_t i = ((size_t)bid * 256 + threadIdx.x) * 8;
        float4 a = *reinterpret_cast<const float4*>(x + i);
        float4 b = *reinterpret_cast<const float4*>(x + i + 4);
        union { u16 u[8]; uint4 v; } o;
        o.u[0]=f2bf(a.x); o.u[1]=f2bf(a.y); o.u[2]=f2bf(a.z); o.u[3]=f2bf(a.w);
        o.u[4]=f2bf(b.x); o.u[5]=f2bf(b.y); o.u[6]=f2bf(b.z); o.u[7]=f2bf(b.w);
        *reinterpret_cast<uint4*>(xb + i) = o.v;
    } else {
        int id  = (bid - 4096) * 256 + threadIdx.x;
        int wi  = id >> 17;
        int rem = id & 131071;
        int kc  = rem >> 10;
        int n   = rem & 1023;
        const float* src = (wi==0) ? w0 : (wi==1) ? w1 : (wi==2) ? w2 : w3;
        union { u16 u[8]; uint4 v; } o;
        #pragma unroll
        for (int i = 0; i < 8; ++i) o.u[i] = f2bf(src[(size_t)(kc*8+i)*1024 + n]);
        *reinterpret_cast<uint4*>(wT + (size_t)wi*1048576 + (size_t)n*1024 + kc*8) = o.v;
    }
}

// ---------------- GEMM: BM=128 x BN=256, 4 waves (2Mx2N), wave=64x128 ----------------
// 3 LDS buffers (72KB) -> 2 WGs/CU; counted vmcnt(6), 1 barrier/iter.
template<int MODE>
__global__ __launch_bounds__(256, 2) void gemm_t(
    const u16* __restrict__ A, const u16* __restrict__ BT,
    const float* __restrict__ bias,
    u16* __restrict__ qh, u16* __restrict__ kh, u16* __restrict__ vh,
    float* __restrict__ outp)
{
    __shared__ u16 SH[36864];                 // 72KB
    u16* Asb = SH;
    u16* Bsb = SH + 12288;

    const int tid  = threadIdx.x;
    const int lane = tid & 63;
    const int wv   = tid >> 6;
    const int wm   = wv >> 1;
    const int wn   = wv & 1;
    const int l15  = lane & 15;
    const int lg   = lane >> 4;

    const int nwg  = gridDim.x;
    const int flat = blockIdx.x;
    const int rid  = (flat & 7) * (nwg >> 3) + (flat >> 3);
    const int NB   = (MODE == 0) ? 12 : 4;
    const int mBlk = rid / NB;
    const int nb   = rid - mBlk * NB;
    const int mBase = mBlk * 128;
    const int nBase = nb * 256;

    const int rS = tid >> 2;
    const int cS = (tid & 3) ^ ((rS >> 1) & 3);
    const u16* aSrc = A  + (size_t)(mBase + rS) * 1024 + cS*8;
    const u16* bSrc = BT + (size_t)(nBase + rS) * 1024 + cS*8;
    const int wb = wv * 512;

    f32x4 acc[4][8];
    #pragma unroll
    for (int i = 0; i < 4; ++i)
        #pragma unroll
        for (int j = 0; j < 8; ++j) acc[i][j] = (f32x4){0.f,0.f,0.f,0.f};

    const int arow = wm*64  + l15;
    const int brow = wn*128 + l15;
    const int aoff = arow*64 + ((lg ^ ((arow >> 1) & 3)) << 4);
    const int boff = brow*64 + ((lg ^ ((brow >> 1) & 3)) << 4);

    auto stg = [&](int buf, int kt) {
        const int ko = kt * 32;
        GLDS16(aSrc + ko,                    &Asb[buf*4096 + wb]);
        GLDS16(aSrc + (size_t)64*1024 + ko,  &Asb[buf*4096 + 2048 + wb]);
        GLDS16(bSrc + ko,                    &Bsb[buf*8192 + wb]);
        GLDS16(bSrc + (size_t)64*1024 + ko,  &Bsb[buf*8192 + 2048 + wb]);
        GLDS16(bSrc + (size_t)128*1024 + ko, &Bsb[buf*8192 + 4096 + wb]);
        GLDS16(bSrc + (size_t)192*1024 + ko, &Bsb[buf*8192 + 6144 + wb]);
    };

    const int NT = 32;
    stg(0, 0);
    stg(1, 1);
    int cur = 0, nxt = 2;
    for (int kt = 0; kt < NT; ++kt) {
        if (kt < NT - 1) asm volatile("s_waitcnt vmcnt(6)" ::: "memory");
        else             asm volatile("s_waitcnt vmcnt(0)" ::: "memory");
        __builtin_amdgcn_s_barrier();
        bf16x8 af[4], bf[8];
        #pragma unroll
        for (int i = 0; i < 4; ++i)
            af[i] = *reinterpret_cast<const bf16x8*>(
                reinterpret_cast<const char*>(&Asb[cur*4096]) + aoff + i*1024);
        #pragma unroll
        for (int j = 0; j < 8; ++j)
            bf[j] = *reinterpret_cast<const bf16x8*>(
                reinterpret_cast<const char*>(&Bsb[cur*8192]) + boff + j*1024);
        if (kt + 2 < NT) stg(nxt, kt + 2);
        asm volatile("s_waitcnt lgkmcnt(0)" ::: "memory");
        __builtin_amdgcn_sched_barrier(0);
        __builtin_amdgcn_s_setprio(1);
        #pragma unroll
        for (int i = 0; i < 4; ++i)
            #pragma unroll
            for (int j = 0; j < 8; ++j)
                acc[i][j] = __builtin_amdgcn_mfma_f32_16x16x32_bf16(af[i], bf[j], acc[i][j], 0, 0, 0);
        __builtin_amdgcn_s_setprio(0);
        cur = (cur == 2) ? 0 : cur + 1;
        nxt = (nxt == 2) ? 0 : nxt + 1;
    }

    const int rbase = lg * 4;

    if (MODE == 0) {
        __syncthreads();
        const int z = nBase >> 10;
        const float fac = (z == 0) ? 0.125f * L2E : 1.0f;
        #pragma unroll
        for (int i = 0; i < 4; ++i)
            #pragma unroll
            for (int j = 0; j < 8; ++j)
                #pragma unroll
                for (int r = 0; r < 4; ++r) {
                    const int row = wm*64 + i*16 + rbase + r;
                    const int col = wn*128 + j*16 + l15;
                    const int ch  = (col >> 3) ^ (row & 7);
                    reinterpret_cast<u16*>(reinterpret_cast<char*>(SH)
                        + row*512 + ch*16)[col & 7] = f2bf(acc[i][j][r] * fac);
                }
        __syncthreads();
        u16* dst = (z == 0) ? qh : (z == 1) ? kh : vh;
        #pragma unroll
        for (int p = 0; p < 16; ++p) {
            const int id  = p*256 + tid;
            const int row = id >> 5;
            const int c16 = id & 31;
            const int ch  = c16 ^ (row & 7);
            uint4 v = *reinterpret_cast<const uint4*>(
                reinterpret_cast<char*>(SH) + row*512 + ch*16);
            const int m = mBase + row;
            const int s = m >> 3, bb = m & 7;
            const int n = nBase + c16*8;
            const int h = (n >> 6) & 15;
            *reinterpret_cast<uint4*>(dst + ((size_t)(bb*NH + h)*SEQ + s)*DH + (n & 63)) = v;
        }
    } else {
        #pragma unroll
        for (int i = 0; i < 4; ++i)
            #pragma unroll
            for (int j = 0; j < 8; ++j)
                #pragma unroll
                for (int r = 0; r < 4; ++r) {
                    const int m = mBase + wm*64 + i*16 + rbase + r;
                    const int n = nBase + wn*128 + j*16 + l15;
                    outp[(size_t)m*1024 + n] = acc[i][j][r] + bias[n];
                }
    }
}

// ------- transpose V + residual, KEY-PERMUTED for b128 PV reads --------
__global__ __launch_bounds__(256) void vtrans_k(const u16* __restrict__ vh,
                                                const float* __restrict__ x,
                                                u16* __restrict__ vt) {
    __shared__ u16 T[64*64];
    const int tid = threadIdx.x;
    const int s0 = blockIdx.x * 64;
    const int bh = blockIdx.y;
    const int b  = bh >> 4;
    const int h  = bh & 15;
    const size_t base = (size_t)bh * (SEQ*DH);
    #pragma unroll
    for (int k = 0; k < 2; ++k) {
        const int idx = k*256 + tid;
        const int r = idx >> 3, c = idx & 7;
        union { uint4 v; u16 u[8]; } val;
        val.v = *reinterpret_cast<const uint4*>(vh + base + (size_t)(s0 + r)*DH + c*8);
        const float* xp = x + ((size_t)(s0 + r)*BSZ + b)*EMB + h*DH + c*8;
        float4 x0 = *reinterpret_cast<const float4*>(xp);
        float4 x1 = *reinterpret_cast<const float4*>(xp + 4);
        val.u[0]=f2bf(bf2f(val.u[0])+x0.x); val.u[1]=f2bf(bf2f(val.u[1])+x0.y);
        val.u[2]=f2bf(bf2f(val.u[2])+x0.z); val.u[3]=f2bf(bf2f(val.u[3])+x0.w);
        val.u[4]=f2bf(bf2f(val.u[4])+x1.x); val.u[5]=f2bf(bf2f(val.u[5])+x1.y);
        val.u[6]=f2bf(bf2f(val.u[6])+x1.z); val.u[7]=f2bf(bf2f(val.u[7])+x1.w);
        const int cs = c ^ (r & 7) ^ ((r >> 3) & 7);
        *reinterpret_cast<uint4*>(reinterpret_cast<char*>(T) + r*128 + cs*16) = val.v;
    }
    __syncthreads();
    #pragma unroll
    for (int k = 0; k < 2; ++k) {
        const int idx = k*256 + tid;
        const int d = idx >> 3, kc = idx & 7;
        union { u16 u[8]; uint2 w[2]; } o;
        #pragma unroll
        for (int i = 0; i < 8; ++i) {
            const int s = kc*8 + i;
            const int ch = (d >> 3) ^ (s & 7) ^ ((s >> 3) & 7);
            o.u[i] = T[s*64 + ch*8 + (d & 7)];
        }
        const int blk = (kc >> 2) * 32;
        const int hbit = (kc >> 1) & 1;
        const int g20 = (2*kc) & 3;
        const int g21 = (2*kc + 1) & 3;
        u16* basep = vt + base + (size_t)d*SEQ + s0 + blk + 4*hbit;
        *reinterpret_cast<uint2*>(basep + 8*g20) = o.w[0];
        *reinterpret_cast<uint2*>(basep + 8*g21) = o.w[1];
    }
}

// ---------------- flash attention: swapped QK^T, in-reg softmax, 2-tile pipeline ----------------
// T15 via MACROS (no array-reference params -> no scratch demotion, rule #20).
// QK^T(kt+1) issued before softmax(kt); 3 K/V buffers; stage(kt+2) after barrier.

#define QK_TILE(BUF, SCN)                                                        \
    {                                                                            \
        const char* kb_ = reinterpret_cast<const char*>(&Kl[BUF][0]) + l15*128;  \
        _Pragma("unroll")                                                        \
        for (int fn = 0; fn < 4; ++fn) {                                         \
            bf16x8 k0_ = *reinterpret_cast<const bf16x8*>(kb_ + fn*2048 + co0);  \
            bf16x8 k1_ = *reinterpret_cast<const bf16x8*>(kb_ + fn*2048 + co1);  \
            _Pragma("unroll")                                                    \
            for (int fq = 0; fq < 2; ++fq) {                                     \
                f32x4 t_ = __builtin_amdgcn_mfma_f32_16x16x32_bf16(k0_, aq[fq][0], \
                            (f32x4){0.f,0.f,0.f,0.f}, 0, 0, 0);                  \
                SCN[fq][fn] = __builtin_amdgcn_mfma_f32_16x16x32_bf16(k1_, aq[fq][1], t_, 0, 0, 0); \
            }                                                                    \
        }                                                                        \
    }

#define BODY(KT, SC, SCN)                                                        \
    {                                                                            \
        const int jb_  = (KT) * KVB;                                            \
        const int nxt_ = (cur == 2) ? 0 : cur + 1;                              \
        if ((KT) + 1 < 16) {                                                    \
            asm volatile("s_waitcnt vmcnt(0)" ::: "memory");                    \
            __builtin_amdgcn_s_barrier();                                       \
            if ((KT) + 2 < 16) {                                                \
                const int st_ = (nxt_ == 2) ? 0 : nxt_ + 1;                     \
                stage(st_, (KT) + 2);                                           \
            }                                                                   \
            QK_TILE(nxt_, SCN)                                                  \
        }                                                                       \
        _Pragma("unroll")                                                       \
        for (int fn = 0; fn < 4; ++fn) {                                        \
            float4 mk_ = *reinterpret_cast<const float4*>(mPtrT + jb_ + fn*16); \
            const float mkf_[4] = {mk_.x, mk_.y, mk_.z, mk_.w};                 \
            _Pragma("unroll")                                                   \
            for (int fq = 0; fq < 2; ++fq)                                      \
                _Pragma("unroll")                                               \
                for (int r = 0; r < 4; ++r)                                     \
                    SC[fq][fn][r] = fmaf(mkf_[r], L2E, SC[fq][fn][r]);          \
        }                                                                       \
        float mx_[2];                                                           \
        _Pragma("unroll")                                                       \
        for (int fq = 0; fq < 2; ++fq) {                                        \
            float m01_ = fmaxf(fmaxf(SC[fq][0][0], SC[fq][0][1]),               \
                               fmaxf(SC[fq][0][2], SC[fq][0][3]));              \
            _Pragma("unroll")                                                   \
            for (int fn = 1; fn < 4; ++fn)                                      \
                m01_ = fmaxf(m01_, fmaxf(fmaxf(SC[fq][fn][0], SC[fq][fn][1]),   \
                                         fmaxf(SC[fq][fn][2], SC[fq][fn][3]))); \
            m01_ = fmaxf(m01_, __shfl_xor(m01_, 16));                           \
            m01_ = fmaxf(m01_, __shfl_xor(m01_, 32));                           \
            mx_[fq] = m01_;                                                     \
        }                                                                       \
        int need_ = (mx_[0] > mrun[0] + 11.5f) | (mx_[1] > mrun[1] + 11.5f);    \
        if (__any(need_)) {                                                     \
            _Pragma("unroll")                                                   \
            for (int fq = 0; fq < 2; ++fq) {                                    \
                const float mn_  = fmaxf(mrun[fq], mx_[fq]);                    \
                const float scl_ = fexp2(mrun[fq] - mn_);                       \
                mrun[fq] = mn_;                                                 \
                lrun[fq] *= scl_;                                               \
                float s4_[4];                                                   \
                _Pragma("unroll")                                               \
                for (int r = 0; r < 4; ++r) s4_[r] = __shfl(scl_, lg*4 + r);    \
                _Pragma("unroll")                                               \
                for (int fd = 0; fd < 4; ++fd)                                  \
                    _Pragma("unroll")                                           \
                    for (int r = 0; r < 4; ++r) o[fq][fd][r] *= s4_[r];         \
            }                                                                   \
        }                                                                       \
        u32 pw_[2][2][4];                                                       \
        _Pragma("unroll")                                                       \
        for (int fq = 0; fq < 2; ++fq) {                                        \
            float rs_ = 0.f;                                                    \
            _Pragma("unroll")                                                   \
            for (int fn = 0; fn < 4; ++fn) {                                    \
                const float p0_ = fexp2(SC[fq][fn][0] - mrun[fq]);              \
                const float p1_ = fexp2(SC[fq][fn][1] - mrun[fq]);              \
                const float p2_ = fexp2(SC[fq][fn][2] - mrun[fq]);              \
                const float p3_ = fexp2(SC[fq][fn][3] - mrun[fq]);              \
                rs_ += (p0_ + p1_) + (p2_ + p3_);                               \
                u32 wA_, wB_;                                                   \
                asm("v_cvt_pk_bf16_f32 %0, %1, %2" : "=v"(wA_) : "v"(p0_), "v"(p1_)); \
                asm("v_cvt_pk_bf16_f32 %0, %1, %2" : "=v"(wB_) : "v"(p2_), "v"(p3_)); \
                pw_[fq][fn >> 1][(fn & 1)*2 + 0] = wA_;                         \
                pw_[fq][fn >> 1][(fn & 1)*2 + 1] = wB_;                         \
            }                                                                   \
            rs_ += __shfl_xor(rs_, 16);                                         \
            rs_ += __shfl_xor(rs_, 32);                                         \
            lrun[fq] += rs_;                                                    \
        }                                                                       \
        const char* vb_ = reinterpret_cast<const char*>(&Vl[cur][0]) + l15*128; \
        _Pragma("unroll")                                                       \
        for (int kk = 0; kk < 2; ++kk) {                                        \
            const int coff_ = kk ? co1 : co0;                                   \
            union { u32 w[4]; bf16x8 v; } pu0_, pu1_;                           \
            pu0_.w[0] = pw_[0][kk][0]; pu0_.w[1] = pw_[0][kk][1];               \
            pu0_.w[2] = pw_[0][kk][2]; pu0_.w[3] = pw_[0][kk][3];               \
            pu1_.w[0] = pw_[1][kk][0]; pu1_.w[1] = pw_[1][kk][1];               \
            pu1_.w[2] = pw_[1][kk][2]; pu1_.w[3] = pw_[1][kk][3];               \
            _Pragma("unroll")                                                   \
            for (int fd = 0; fd < 4; ++fd) {                                    \
                bf16x8 vf_ = *reinterpret_cast<const bf16x8*>(vb_ + fd*2048 + coff_); \
                o[0][fd] = __builtin_amdgcn_mfma_f32_16x16x32_bf16(pu0_.v, vf_, o[0][fd], 0, 0, 0); \
                o[1][fd] = __builtin_amdgcn_mfma_f32_16x16x32_bf16(pu1_.v, vf_, o[1][fd], 0, 0, 0); \
            }                                                                   \
        }                                                                       \
        cur = nxt_;                                                             \
    }

__global__ __launch_bounds__(256, 3) void attn_k(
    const u16* __restrict__ qh, const u16* __restrict__ kh,
    const u16* __restrict__ vt, const float* __restrict__ mask,
    u16* __restrict__ ctx)
{
    __shared__ u16 Kl[3][KVB*64];   // [key][d], 16B chunks ^ (key&7)
    __shared__ u16 Vl[3][KVB*64];   // [d][permuted key], 16B chunks ^ (d&7)

    const int tid  = threadIdx.x;
    const int lane = tid & 63;
    const int wv   = tid >> 6;
    const int l15  = lane & 15;
    const int lg   = lane >> 4;

    const int d0 = blockIdx.y * 8 + blockIdx.x;
    const int bh = (d0 & 7) * 16 + (d0 >> 6);
    const int qt = (d0 >> 3) & 7;
    const int b  = bh >> 4;
    const int h  = bh & 15;
    const int qbase = qt * 128;
    const size_t bhOff = (size_t)bh * (SEQ*DH);

    const int rS = tid >> 3;
    const int cS = (tid & 7) ^ (rS & 7);
    const u16* kSrc = kh + bhOff + (size_t)rS*DH  + cS*8;
    const u16* vSrc = vt + bhOff + (size_t)rS*SEQ + cS*8;
    const int ldst = wv * 512;

    bf16x8 aq[2][2];
    #pragma unroll
    for (int fq = 0; fq < 2; ++fq)
        #pragma unroll
        for (int kk = 0; kk < 2; ++kk)
            aq[fq][kk] = *reinterpret_cast<const bf16x8*>(
                qh + bhOff + (size_t)(qbase + wv*32 + fq*16 + l15)*DH + kk*32 + lg*8);

    f32x4 o[2][4];
    float mrun[2], lrun[2];
    #pragma unroll
    for (int fq = 0; fq < 2; ++fq) {
        #pragma unroll
        for (int fd = 0; fd < 4; ++fd) o[fq][fd] = (f32x4){0.f,0.f,0.f,0.f};
        mrun[fq] = -1e30f; lrun[fq] = 0.f;
    }

    const int co0 = ((lg)     ^ (l15 & 7)) << 4;
    const int co1 = ((4 + lg) ^ (l15 & 7)) << 4;
    const float* mPtrT = mask + (size_t)b*SEQ + lg*4;

    auto stage = [&](int buf, int kt) {
        const int jb = kt * KVB;
        GLDS16(kSrc + (size_t)jb*DH,        &Kl[buf][ldst]);
        GLDS16(kSrc + (size_t)(jb+32)*DH,   &Kl[buf][2048 + ldst]);
        GLDS16(vSrc + jb,                   &Vl[buf][ldst]);
        GLDS16(vSrc + 32*SEQ + jb,          &Vl[buf][2048 + ldst]);
    };

    int cur = 0;
    f32x4 scA[2][4], scB[2][4];

    // prologue: stage 0, wait+barrier, stage 1, QK(0)
    stage(0, 0);
    asm volatile("s_waitcnt vmcnt(0)" ::: "memory");
    __builtin_amdgcn_s_barrier();
    stage(1, 1);
    QK_TILE(0, scA)

    for (int kt = 0; kt < 16; kt += 2) {
        BODY(kt,     scA, scB)
        BODY(kt + 1, scB, scA)
    }

    #pragma unroll
    for (int fq = 0; fq < 2; ++fq) {
        const float linv = 1.0f / lrun[fq];
        float inv4[4];
        #pragma unroll
        for (int r = 0; r < 4; ++r) inv4[r] = __shfl(linv, lg*4 + r);
        #pragma unroll
        for (int r = 0; r < 4; ++r) {
            const int s = qbase + wv*32 + fq*16 + lg*4 + r;
            #pragma unroll
            for (int fd = 0; fd < 4; ++fd) {
                const int d = fd*16 + l15;
                ctx[((size_t)(s*BSZ + b))*EMB + h*DH + d] = f2bf(o[fq][fd][r] * inv4[r]);
            }
        }
    }
}

extern "C" void kernel_launch(void* const* d_in, const int* in_sizes, int n_in,
                              void* d_out, int out_size, void* d_ws, size_t ws_size,
                              hipStream_t stream) {
    const float* x    = (const float*)d_in[0];
    const float* mask = (const float*)d_in[1];
    const float* w_q  = (const float*)d_in[2];
    const float* w_k  = (const float*)d_in[3];
    const float* w_v  = (const float*)d_in[4];
    const float* w_o  = (const float*)d_in[5];
    const float* b_o  = (const float*)d_in[6];

    char* ws = (char*)d_ws;
    u16* xb  = (u16*)(ws);                        // 16 MB
    u16* wT  = (u16*)(ws + ((size_t)16 << 20));   // 8 MB
    u16* qh  = (u16*)(ws + ((size_t)24 << 20));   // 16 MB
    u16* kh  = (u16*)(ws + ((size_t)40 << 20));   // 16 MB
    u16* vt  = (u16*)(ws + ((size_t)56 << 20));   // 16 MB (V transposed + key-permuted)
    u16* vh  = (u16*)(ws + ((size_t)72 << 20));   // 16 MB
    u16* ctx = vh;                                // vh dead after vtrans
    float* outp = (float*)d_out;

    cvt_k<<<6144, 256, 0, stream>>>(x, w_q, w_k, w_v, w_o, xb, wT);
    gemm_t<0><<<768, 256, 0, stream>>>(xb, wT, nullptr, qh, kh, vh, nullptr);
    vtrans_k<<<dim3(16, 128), 256, 0, stream>>>(vh, x, vt);
    attn_k<<<dim3(8, 128), 256, 0, stream>>>(qh, kh, vt, mask, ctx);
    gemm_t<1><<<256, 256, 0, stream>>>(ctx, wT + (size_t)3*1048576, b_o,
                                       nullptr, nullptr, nullptr, outp);
}

// Round 13
// 181.449 us; speedup vs baseline: 1.1523x; 1.1523x over previous
//
#include <hip/hip_runtime.h>

typedef unsigned short u16;
typedef unsigned int   u32;
typedef __attribute__((ext_vector_type(8))) short bf16x8;
typedef __attribute__((ext_vector_type(4))) float f32x4;

#define SEQ 1024
#define BSZ 8
#define EMB 1024
#define NH  16
#define DH  64
#define KVB 64
#define L2E 1.44269504088896f

__device__ __forceinline__ u16 f2bf(float f) {
    u32 u = __float_as_uint(f);
    u32 r = u + 0x7FFFu + ((u >> 16) & 1u);   // round-to-nearest-even
    return (u16)(r >> 16);
}
__device__ __forceinline__ float bf2f(u16 u) {
    return __uint_as_float((u32)u << 16);
}
__device__ __forceinline__ float fexp2(float x) {
    return __builtin_amdgcn_exp2f(x);
}

#define GLDS16(g, l) __builtin_amdgcn_global_load_lds( \
    (const __attribute__((address_space(1))) void*)(g), \
    (__attribute__((address_space(3))) void*)(l), 16, 0, 0)

// ------- merged convert: x (fp32)->xb (bf16); w (K,N) fp32 -> wT (N,K) bf16 -------
__global__ __launch_bounds__(256) void cvt_k(
    const float* __restrict__ x, const float* __restrict__ w0,
    const float* __restrict__ w1, const float* __restrict__ w2,
    const float* __restrict__ w3, u16* __restrict__ xb, u16* __restrict__ wT)
{
    const int bid = blockIdx.x;
    if (bid < 4096) {
        size_t i = ((size_t)bid * 256 + threadIdx.x) * 8;
        float4 a = *reinterpret_cast<const float4*>(x + i);
        float4 b = *reinterpret_cast<const float4*>(x + i + 4);
        union { u16 u[8]; uint4 v; } o;
        o.u[0]=f2bf(a.x); o.u[1]=f2bf(a.y); o.u[2]=f2bf(a.z); o.u[3]=f2bf(a.w);
        o.u[4]=f2bf(b.x); o.u[5]=f2bf(b.y); o.u[6]=f2bf(b.z); o.u[7]=f2bf(b.w);
        *reinterpret_cast<uint4*>(xb + i) = o.v;
    } else {
        int id  = (bid - 4096) * 256 + threadIdx.x;
        int wi  = id >> 17;
        int rem = id & 131071;
        int kc  = rem >> 10;
        int n   = rem & 1023;
        const float* src = (wi==0) ? w0 : (wi==1) ? w1 : (wi==2) ? w2 : w3;
        union { u16 u[8]; uint4 v; } o;
        #pragma unroll
        for (int i = 0; i < 8; ++i) o.u[i] = f2bf(src[(size_t)(kc*8+i)*1024 + n]);
        *reinterpret_cast<uint4*>(wT + (size_t)wi*1048576 + (size_t)n*1024 + kc*8) = o.v;
    }
}

// ---------------- GEMM: BM=128 x BN=256, 4 waves (2Mx2N), wave=64x128 ----------------
// 3 LDS buffers (72KB) -> 2 WGs/CU; counted vmcnt(6), 1 barrier/iter.
template<int MODE>
__global__ __launch_bounds__(256, 2) void gemm_t(
    const u16* __restrict__ A, const u16* __restrict__ BT,
    const float* __restrict__ bias,
    u16* __restrict__ qh, u16* __restrict__ kh, u16* __restrict__ vh,
    float* __restrict__ outp)
{
    __shared__ u16 SH[36864];                 // 72KB
    u16* Asb = SH;
    u16* Bsb = SH + 12288;

    const int tid  = threadIdx.x;
    const int lane = tid & 63;
    const int wv   = tid >> 6;
    const int wm   = wv >> 1;
    const int wn   = wv & 1;
    const int l15  = lane & 15;
    const int lg   = lane >> 4;

    const int nwg  = gridDim.x;
    const int flat = blockIdx.x;
    const int rid  = (flat & 7) * (nwg >> 3) + (flat >> 3);
    const int NB   = (MODE == 0) ? 12 : 4;
    const int mBlk = rid / NB;
    const int nb   = rid - mBlk * NB;
    const int mBase = mBlk * 128;
    const int nBase = nb * 256;

    const int rS = tid >> 2;
    const int cS = (tid & 3) ^ ((rS >> 1) & 3);
    const u16* aSrc = A  + (size_t)(mBase + rS) * 1024 + cS*8;
    const u16* bSrc = BT + (size_t)(nBase + rS) * 1024 + cS*8;
    const int wb = wv * 512;

    f32x4 acc[4][8];
    #pragma unroll
    for (int i = 0; i < 4; ++i)
        #pragma unroll
        for (int j = 0; j < 8; ++j) acc[i][j] = (f32x4){0.f,0.f,0.f,0.f};

    const int arow = wm*64  + l15;
    const int brow = wn*128 + l15;
    const int aoff = arow*64 + ((lg ^ ((arow >> 1) & 3)) << 4);
    const int boff = brow*64 + ((lg ^ ((brow >> 1) & 3)) << 4);

    auto stg = [&](int buf, int kt) {
        const int ko = kt * 32;
        GLDS16(aSrc + ko,                    &Asb[buf*4096 + wb]);
        GLDS16(aSrc + (size_t)64*1024 + ko,  &Asb[buf*4096 + 2048 + wb]);
        GLDS16(bSrc + ko,                    &Bsb[buf*8192 + wb]);
        GLDS16(bSrc + (size_t)64*1024 + ko,  &Bsb[buf*8192 + 2048 + wb]);
        GLDS16(bSrc + (size_t)128*1024 + ko, &Bsb[buf*8192 + 4096 + wb]);
        GLDS16(bSrc + (size_t)192*1024 + ko, &Bsb[buf*8192 + 6144 + wb]);
    };

    const int NT = 32;
    stg(0, 0);
    stg(1, 1);
    int cur = 0, nxt = 2;
    for (int kt = 0; kt < NT; ++kt) {
        if (kt < NT - 1) asm volatile("s_waitcnt vmcnt(6)" ::: "memory");
        else             asm volatile("s_waitcnt vmcnt(0)" ::: "memory");
        __builtin_amdgcn_s_barrier();
        bf16x8 af[4], bf[8];
        #pragma unroll
        for (int i = 0; i < 4; ++i)
            af[i] = *reinterpret_cast<const bf16x8*>(
                reinterpret_cast<const char*>(&Asb[cur*4096]) + aoff + i*1024);
        #pragma unroll
        for (int j = 0; j < 8; ++j)
            bf[j] = *reinterpret_cast<const bf16x8*>(
                reinterpret_cast<const char*>(&Bsb[cur*8192]) + boff + j*1024);
        if (kt + 2 < NT) stg(nxt, kt + 2);
        asm volatile("s_waitcnt lgkmcnt(0)" ::: "memory");
        __builtin_amdgcn_sched_barrier(0);
        __builtin_amdgcn_s_setprio(1);
        #pragma unroll
        for (int i = 0; i < 4; ++i)
            #pragma unroll
            for (int j = 0; j < 8; ++j)
                acc[i][j] = __builtin_amdgcn_mfma_f32_16x16x32_bf16(af[i], bf[j], acc[i][j], 0, 0, 0);
        __builtin_amdgcn_s_setprio(0);
        cur = (cur == 2) ? 0 : cur + 1;
        nxt = (nxt == 2) ? 0 : nxt + 1;
    }

    const int rbase = lg * 4;

    if (MODE == 0) {
        __syncthreads();
        const int z = nBase >> 10;
        const float fac = (z == 0) ? 0.125f * L2E : 1.0f;
        #pragma unroll
        for (int i = 0; i < 4; ++i)
            #pragma unroll
            for (int j = 0; j < 8; ++j)
                #pragma unroll
                for (int r = 0; r < 4; ++r) {
                    const int row = wm*64 + i*16 + rbase + r;
                    const int col = wn*128 + j*16 + l15;
                    const int ch  = (col >> 3) ^ (row & 7);
                    reinterpret_cast<u16*>(reinterpret_cast<char*>(SH)
                        + row*512 + ch*16)[col & 7] = f2bf(acc[i][j][r] * fac);
                }
        __syncthreads();
        u16* dst = (z == 0) ? qh : (z == 1) ? kh : vh;
        #pragma unroll
        for (int p = 0; p < 16; ++p) {
            const int id  = p*256 + tid;
            const int row = id >> 5;
            const int c16 = id & 31;
            const int ch  = c16 ^ (row & 7);
            uint4 v = *reinterpret_cast<const uint4*>(
                reinterpret_cast<char*>(SH) + row*512 + ch*16);
            const int m = mBase + row;
            const int s = m >> 3, bb = m & 7;
            const int n = nBase + c16*8;
            const int h = (n >> 6) & 15;
            *reinterpret_cast<uint4*>(dst + ((size_t)(bb*NH + h)*SEQ + s)*DH + (n & 63)) = v;
        }
    } else {
        #pragma unroll
        for (int i = 0; i < 4; ++i)
            #pragma unroll
            for (int j = 0; j < 8; ++j)
                #pragma unroll
                for (int r = 0; r < 4; ++r) {
                    const int m = mBase + wm*64 + i*16 + rbase + r;
                    const int n = nBase + wn*128 + j*16 + l15;
                    outp[(size_t)m*1024 + n] = acc[i][j][r] + bias[n];
                }
    }
}

// ------- transpose V + residual, KEY-PERMUTED for b128 PV reads --------
__global__ __launch_bounds__(256) void vtrans_k(const u16* __restrict__ vh,
                                                const float* __restrict__ x,
                                                u16* __restrict__ vt) {
    __shared__ u16 T[64*64];
    const int tid = threadIdx.x;
    const int s0 = blockIdx.x * 64;
    const int bh = blockIdx.y;
    const int b  = bh >> 4;
    const int h  = bh & 15;
    const size_t base = (size_t)bh * (SEQ*DH);
    #pragma unroll
    for (int k = 0; k < 2; ++k) {
        const int idx = k*256 + tid;
        const int r = idx >> 3, c = idx & 7;
        union { uint4 v; u16 u[8]; } val;
        val.v = *reinterpret_cast<const uint4*>(vh + base + (size_t)(s0 + r)*DH + c*8);
        const float* xp = x + ((size_t)(s0 + r)*BSZ + b)*EMB + h*DH + c*8;
        float4 x0 = *reinterpret_cast<const float4*>(xp);
        float4 x1 = *reinterpret_cast<const float4*>(xp + 4);
        val.u[0]=f2bf(bf2f(val.u[0])+x0.x); val.u[1]=f2bf(bf2f(val.u[1])+x0.y);
        val.u[2]=f2bf(bf2f(val.u[2])+x0.z); val.u[3]=f2bf(bf2f(val.u[3])+x0.w);
        val.u[4]=f2bf(bf2f(val.u[4])+x1.x); val.u[5]=f2bf(bf2f(val.u[5])+x1.y);
        val.u[6]=f2bf(bf2f(val.u[6])+x1.z); val.u[7]=f2bf(bf2f(val.u[7])+x1.w);
        const int cs = c ^ (r & 7) ^ ((r >> 3) & 7);
        *reinterpret_cast<uint4*>(reinterpret_cast<char*>(T) + r*128 + cs*16) = val.v;
    }
    __syncthreads();
    #pragma unroll
    for (int k = 0; k < 2; ++k) {
        const int idx = k*256 + tid;
        const int d = idx >> 3, kc = idx & 7;
        union { u16 u[8]; uint2 w[2]; } o;
        #pragma unroll
        for (int i = 0; i < 8; ++i) {
            const int s = kc*8 + i;
            const int ch = (d >> 3) ^ (s & 7) ^ ((s >> 3) & 7);
            o.u[i] = T[s*64 + ch*8 + (d & 7)];
        }
        const int blk = (kc >> 2) * 32;
        const int hbit = (kc >> 1) & 1;
        const int g20 = (2*kc) & 3;
        const int g21 = (2*kc + 1) & 3;
        u16* basep = vt + base + (size_t)d*SEQ + s0 + blk + 4*hbit;
        *reinterpret_cast<uint2*>(basep + 8*g20) = o.w[0];
        *reinterpret_cast<uint2*>(basep + 8*g21) = o.w[1];
    }
}

// ---------------- flash attention: swapped QK^T, in-register softmax ----------------
// R9-proven math, q-tile split 128->64 rows (wave owns 16 q-rows) for occupancy:
// 32KB LDS -> 5 blocks/CU; grid 2048 blocks; XCD-bijective remap keeps per-XCD
// K/V working set ~4MB (L2-resident).
__global__ __launch_bounds__(256, 5) void attn_k(
    const u16* __restrict__ qh, const u16* __restrict__ kh,
    const u16* __restrict__ vt, const float* __restrict__ mask,
    u16* __restrict__ ctx)
{
    __shared__ u16 Kl[2][KVB*64];   // [key][d], 16B chunks ^ (key&7)
    __shared__ u16 Vl[2][KVB*64];   // [d][permuted key], 16B chunks ^ (d&7)

    const int tid  = threadIdx.x;
    const int lane = tid & 63;
    const int wv   = tid >> 6;
    const int l15  = lane & 15;
    const int lg   = lane >> 4;

    // flat in [0,2048): bits [b3..b0][q3..q0][x2..x0]
    const int flat = blockIdx.y * 16 + blockIdx.x;
    const int bh = (flat & 7) * 16 + ((flat >> 7) & 15);
    const int qt = (flat >> 3) & 15;
    const int b  = bh >> 4;
    const int h  = bh & 15;
    const int qbase = qt * 64;
    const size_t bhOff = (size_t)bh * (SEQ*DH);

    const int rS = tid >> 3;
    const int cS = (tid & 7) ^ (rS & 7);
    const u16* kSrc = kh + bhOff + (size_t)rS*DH  + cS*8;
    const u16* vSrc = vt + bhOff + (size_t)rS*SEQ + cS*8;
    const int ldst = wv * 512;

    // Q fragments (B-operand): col = q = l15 within wave's 16-row block
    bf16x8 aq[2];
    #pragma unroll
    for (int kk = 0; kk < 2; ++kk)
        aq[kk] = *reinterpret_cast<const bf16x8*>(
            qh + bhOff + (size_t)(qbase + wv*16 + l15)*DH + kk*32 + lg*8);

    f32x4 o[4];
    float mrun = -1e30f, lrun = 0.f;
    #pragma unroll
    for (int fd = 0; fd < 4; ++fd) o[fd] = (f32x4){0.f,0.f,0.f,0.f};

    const int co0 = ((lg)     ^ (l15 & 7)) << 4;
    const int co1 = ((4 + lg) ^ (l15 & 7)) << 4;
    const float* mPtrT = mask + (size_t)b*SEQ + lg*4;

    auto stage = [&](int buf, int kt) {
        const int jb = kt * KVB;
        GLDS16(kSrc + (size_t)jb*DH,        &Kl[buf][ldst]);
        GLDS16(kSrc + (size_t)(jb+32)*DH,   &Kl[buf][2048 + ldst]);
        GLDS16(vSrc + jb,                   &Vl[buf][ldst]);
        GLDS16(vSrc + 32*SEQ + jb,          &Vl[buf][2048 + ldst]);
    };

    stage(0, 0);
    int cur = 0;

    for (int kt = 0; kt < 16; ++kt) {
        __syncthreads();
        if (kt + 1 < 16) stage(cur ^ 1, kt + 1);
        const int jb = kt * KVB;

        // ---- ST = K·Q^T: lane holds S[key=fn*16+lg*4+r][q=l15] ----
        f32x4 sc[4];
        const char* kb = reinterpret_cast<const char*>(&Kl[cur][0]) + l15*128;
        #pragma unroll
        for (int fn = 0; fn < 4; ++fn) {
            bf16x8 k0 = *reinterpret_cast<const bf16x8*>(kb + fn*2048 + co0);
            bf16x8 k1 = *reinterpret_cast<const bf16x8*>(kb + fn*2048 + co1);
            f32x4 t = __builtin_amdgcn_mfma_f32_16x16x32_bf16(k0, aq[0],
                        (f32x4){0.f,0.f,0.f,0.f}, 0, 0, 0);
            sc[fn] = __builtin_amdgcn_mfma_f32_16x16x32_bf16(k1, aq[1], t, 0, 0, 0);
        }
        // ---- mask (log2 domain) ----
        #pragma unroll
        for (int fn = 0; fn < 4; ++fn) {
            float4 mk = *reinterpret_cast<const float4*>(mPtrT + jb + fn*16);
            const float mkf[4] = {mk.x, mk.y, mk.z, mk.w};
            #pragma unroll
            for (int r = 0; r < 4; ++r)
                sc[fn][r] = fmaf(mkf[r], L2E, sc[fn][r]);
        }
        // ---- max: in-lane over 16, then lg-groups via 2 shfl ----
        float mx = fmaxf(fmaxf(sc[0][0], sc[0][1]), fmaxf(sc[0][2], sc[0][3]));
        #pragma unroll
        for (int fn = 1; fn < 4; ++fn)
            mx = fmaxf(mx, fmaxf(fmaxf(sc[fn][0], sc[fn][1]),
                                 fmaxf(sc[fn][2], sc[fn][3])));
        mx = fmaxf(mx, __shfl_xor(mx, 16));
        mx = fmaxf(mx, __shfl_xor(mx, 32));
        // ---- defer-max rescale (log2 domain, THR = 8*log2e) ----
        int need = (mx > mrun + 11.5f);
        if (__any(need)) {
            const float mn  = fmaxf(mrun, mx);
            const float scl = fexp2(mrun - mn);
            mrun = mn;
            lrun *= scl;
            float s4[4];
            #pragma unroll
            for (int r = 0; r < 4; ++r) s4[r] = __shfl(scl, lg*4 + r);
            #pragma unroll
            for (int fd = 0; fd < 4; ++fd)
                #pragma unroll
                for (int r = 0; r < 4; ++r) o[fd][r] *= s4[r];
        }
        // ---- P = exp2(sc - m), pack (A-frag under pi), row-sum ----
        u32 pw[2][4];
        float rs = 0.f;
        #pragma unroll
        for (int fn = 0; fn < 4; ++fn) {
            const float p0 = fexp2(sc[fn][0] - mrun);
            const float p1 = fexp2(sc[fn][1] - mrun);
            const float p2 = fexp2(sc[fn][2] - mrun);
            const float p3 = fexp2(sc[fn][3] - mrun);
            rs += (p0 + p1) + (p2 + p3);
            u32 wA, wB;
            asm("v_cvt_pk_bf16_f32 %0, %1, %2" : "=v"(wA) : "v"(p0), "v"(p1));
            asm("v_cvt_pk_bf16_f32 %0, %1, %2" : "=v"(wB) : "v"(p2), "v"(p3));
            pw[fn >> 1][(fn & 1)*2 + 0] = wA;
            pw[fn >> 1][(fn & 1)*2 + 1] = wB;
        }
        rs += __shfl_xor(rs, 16);
        rs += __shfl_xor(rs, 32);
        lrun += rs;
        bf16x8 pa[2];
        #pragma unroll
        for (int kk = 0; kk < 2; ++kk) {
            union { u32 w[4]; bf16x8 v; } u;
            u.w[0] = pw[kk][0]; u.w[1] = pw[kk][1];
            u.w[2] = pw[kk][2]; u.w[3] = pw[kk][3];
            pa[kk] = u.v;
        }
        // ---- O += P·V : V pre-permuted -> b128 reads at K-read offsets ----
        const char* vb = reinterpret_cast<const char*>(&Vl[cur][0]) + l15*128;
        #pragma unroll
        for (int kk = 0; kk < 2; ++kk) {
            const int coff = kk ? co1 : co0;
            #pragma unroll
            for (int fd = 0; fd < 4; ++fd) {
                bf16x8 vf = *reinterpret_cast<const bf16x8*>(vb + fd*2048 + coff);
                o[fd] = __builtin_amdgcn_mfma_f32_16x16x32_bf16(pa[kk], vf, o[fd], 0, 0, 0);
            }
        }
        cur ^= 1;
    }

    // ---- epilogue: o[fd][r] is (q = wv*16 + lg*4 + r, d = fd*16 + l15) ----
    const float linv = 1.0f / lrun;
    float inv4[4];
    #pragma unroll
    for (int r = 0; r < 4; ++r) inv4[r] = __shfl(linv, lg*4 + r);
    #pragma unroll
    for (int r = 0; r < 4; ++r) {
        const int s = qbase + wv*16 + lg*4 + r;
        #pragma unroll
        for (int fd = 0; fd < 4; ++fd) {
            const int d = fd*16 + l15;
            ctx[((size_t)(s*BSZ + b))*EMB + h*DH + d] = f2bf(o[fd][r] * inv4[r]);
        }
    }
}

extern "C" void kernel_launch(void* const* d_in, const int* in_sizes, int n_in,
                              void* d_out, int out_size, void* d_ws, size_t ws_size,
                              hipStream_t stream) {
    const float* x    = (const float*)d_in[0];
    const float* mask = (const float*)d_in[1];
    const float* w_q  = (const float*)d_in[2];
    const float* w_k  = (const float*)d_in[3];
    const float* w_v  = (const float*)d_in[4];
    const float* w_o  = (const float*)d_in[5];
    const float* b_o  = (const float*)d_in[6];

    char* ws = (char*)d_ws;
    u16* xb  = (u16*)(ws);                        // 16 MB
    u16* wT  = (u16*)(ws + ((size_t)16 << 20));   // 8 MB
    u16* qh  = (u16*)(ws + ((size_t)24 << 20));   // 16 MB
    u16* kh  = (u16*)(ws + ((size_t)40 << 20));   // 16 MB
    u16* vt  = (u16*)(ws + ((size_t)56 << 20));   // 16 MB (V transposed + key-permuted)
    u16* vh  = (u16*)(ws + ((size_t)72 << 20));   // 16 MB
    u16* ctx = vh;                                // vh dead after vtrans
    float* outp = (float*)d_out;

    cvt_k<<<6144, 256, 0, stream>>>(x, w_q, w_k, w_v, w_o, xb, wT);
    gemm_t<0><<<768, 256, 0, stream>>>(xb, wT, nullptr, qh, kh, vh, nullptr);
    vtrans_k<<<dim3(16, 128), 256, 0, stream>>>(vh, x, vt);
    attn_k<<<dim3(16, 128), 256, 0, stream>>>(qh, kh, vt, mask, ctx);
    gemm_t<1><<<256, 256, 0, stream>>>(ctx, wT + (size_t)3*1048576, b_o,
                                       nullptr, nullptr, nullptr, outp);
}

// Round 14
// 173.952 us; speedup vs baseline: 1.2020x; 1.0431x over previous
//
#include <hip/hip_runtime.h>

typedef unsigned short u16;
typedef unsigned int   u32;
typedef __attribute__((ext_vector_type(8))) short bf16x8;
typedef __attribute__((ext_vector_type(4))) float f32x4;

#define SEQ 1024
#define BSZ 8
#define EMB 1024
#define NH  16
#define DH  64
#define KVB 64
#define L2E 1.44269504088896f

__device__ __forceinline__ u16 f2bf(float f) {
    u32 u = __float_as_uint(f);
    u32 r = u + 0x7FFFu + ((u >> 16) & 1u);   // round-to-nearest-even
    return (u16)(r >> 16);
}
__device__ __forceinline__ float bf2f(u16 u) {
    return __uint_as_float((u32)u << 16);
}
__device__ __forceinline__ float fexp2(float x) {
    return __builtin_amdgcn_exp2f(x);
}

#define GLDS16(g, l) __builtin_amdgcn_global_load_lds( \
    (const __attribute__((address_space(1))) void*)(g), \
    (__attribute__((address_space(3))) void*)(l), 16, 0, 0)

// ------- merged convert: x (fp32)->xb (bf16); w (K,N) fp32 -> wT (N,K) bf16 -------
__global__ __launch_bounds__(256) void cvt_k(
    const float* __restrict__ x, const float* __restrict__ w0,
    const float* __restrict__ w1, const float* __restrict__ w2,
    const float* __restrict__ w3, u16* __restrict__ xb, u16* __restrict__ wT)
{
    const int bid = blockIdx.x;
    if (bid < 4096) {
        size_t i = ((size_t)bid * 256 + threadIdx.x) * 8;
        float4 a = *reinterpret_cast<const float4*>(x + i);
        float4 b = *reinterpret_cast<const float4*>(x + i + 4);
        union { u16 u[8]; uint4 v; } o;
        o.u[0]=f2bf(a.x); o.u[1]=f2bf(a.y); o.u[2]=f2bf(a.z); o.u[3]=f2bf(a.w);
        o.u[4]=f2bf(b.x); o.u[5]=f2bf(b.y); o.u[6]=f2bf(b.z); o.u[7]=f2bf(b.w);
        *reinterpret_cast<uint4*>(xb + i) = o.v;
    } else {
        int id  = (bid - 4096) * 256 + threadIdx.x;
        int wi  = id >> 17;
        int rem = id & 131071;
        int kc  = rem >> 10;
        int n   = rem & 1023;
        const float* src = (wi==0) ? w0 : (wi==1) ? w1 : (wi==2) ? w2 : w3;
        union { u16 u[8]; uint4 v; } o;
        #pragma unroll
        for (int i = 0; i < 8; ++i) o.u[i] = f2bf(src[(size_t)(kc*8+i)*1024 + n]);
        *reinterpret_cast<uint4*>(wT + (size_t)wi*1048576 + (size_t)n*1024 + kc*8) = o.v;
    }
}

// ---------------- GEMM: BM=128 x BN=256, 4 waves (2Mx2N), wave=64x128 ----------------
// 3 LDS buffers (72KB) -> 2 WGs/CU; counted vmcnt(6), 1 barrier/iter.
template<int MODE>
__global__ __launch_bounds__(256, 2) void gemm_t(
    const u16* __restrict__ A, const u16* __restrict__ BT,
    const float* __restrict__ bias,
    u16* __restrict__ qh, u16* __restrict__ kh, u16* __restrict__ vh,
    float* __restrict__ outp)
{
    __shared__ u16 SH[36864];                 // 72KB
    u16* Asb = SH;
    u16* Bsb = SH + 12288;

    const int tid  = threadIdx.x;
    const int lane = tid & 63;
    const int wv   = tid >> 6;
    const int wm   = wv >> 1;
    const int wn   = wv & 1;
    const int l15  = lane & 15;
    const int lg   = lane >> 4;

    const int nwg  = gridDim.x;
    const int flat = blockIdx.x;
    const int rid  = (flat & 7) * (nwg >> 3) + (flat >> 3);
    const int NB   = (MODE == 0) ? 12 : 4;
    const int mBlk = rid / NB;
    const int nb   = rid - mBlk * NB;
    const int mBase = mBlk * 128;
    const int nBase = nb * 256;

    const int rS = tid >> 2;
    const int cS = (tid & 3) ^ ((rS >> 1) & 3);
    const u16* aSrc = A  + (size_t)(mBase + rS) * 1024 + cS*8;
    const u16* bSrc = BT + (size_t)(nBase + rS) * 1024 + cS*8;
    const int wb = wv * 512;

    f32x4 acc[4][8];
    #pragma unroll
    for (int i = 0; i < 4; ++i)
        #pragma unroll
        for (int j = 0; j < 8; ++j) acc[i][j] = (f32x4){0.f,0.f,0.f,0.f};

    const int arow = wm*64  + l15;
    const int brow = wn*128 + l15;
    const int aoff = arow*64 + ((lg ^ ((arow >> 1) & 3)) << 4);
    const int boff = brow*64 + ((lg ^ ((brow >> 1) & 3)) << 4);

    auto stg = [&](int buf, int kt) {
        const int ko = kt * 32;
        GLDS16(aSrc + ko,                    &Asb[buf*4096 + wb]);
        GLDS16(aSrc + (size_t)64*1024 + ko,  &Asb[buf*4096 + 2048 + wb]);
        GLDS16(bSrc + ko,                    &Bsb[buf*8192 + wb]);
        GLDS16(bSrc + (size_t)64*1024 + ko,  &Bsb[buf*8192 + 2048 + wb]);
        GLDS16(bSrc + (size_t)128*1024 + ko, &Bsb[buf*8192 + 4096 + wb]);
        GLDS16(bSrc + (size_t)192*1024 + ko, &Bsb[buf*8192 + 6144 + wb]);
    };

    const int NT = 32;
    stg(0, 0);
    stg(1, 1);
    int cur = 0, nxt = 2;
    for (int kt = 0; kt < NT; ++kt) {
        if (kt < NT - 1) asm volatile("s_waitcnt vmcnt(6)" ::: "memory");
        else             asm volatile("s_waitcnt vmcnt(0)" ::: "memory");
        __builtin_amdgcn_s_barrier();
        bf16x8 af[4], bf[8];
        #pragma unroll
        for (int i = 0; i < 4; ++i)
            af[i] = *reinterpret_cast<const bf16x8*>(
                reinterpret_cast<const char*>(&Asb[cur*4096]) + aoff + i*1024);
        #pragma unroll
        for (int j = 0; j < 8; ++j)
            bf[j] = *reinterpret_cast<const bf16x8*>(
                reinterpret_cast<const char*>(&Bsb[cur*8192]) + boff + j*1024);
        if (kt + 2 < NT) stg(nxt, kt + 2);
        asm volatile("s_waitcnt lgkmcnt(0)" ::: "memory");
        __builtin_amdgcn_sched_barrier(0);
        __builtin_amdgcn_s_setprio(1);
        #pragma unroll
        for (int i = 0; i < 4; ++i)
            #pragma unroll
            for (int j = 0; j < 8; ++j)
                acc[i][j] = __builtin_amdgcn_mfma_f32_16x16x32_bf16(af[i], bf[j], acc[i][j], 0, 0, 0);
        __builtin_amdgcn_s_setprio(0);
        cur = (cur == 2) ? 0 : cur + 1;
        nxt = (nxt == 2) ? 0 : nxt + 1;
    }

    const int rbase = lg * 4;

    if (MODE == 0) {
        __syncthreads();
        const int z = nBase >> 10;
        const float fac = (z == 0) ? 0.125f * L2E : 1.0f;
        #pragma unroll
        for (int i = 0; i < 4; ++i)
            #pragma unroll
            for (int j = 0; j < 8; ++j)
                #pragma unroll
                for (int r = 0; r < 4; ++r) {
                    const int row = wm*64 + i*16 + rbase + r;
                    const int col = wn*128 + j*16 + l15;
                    const int ch  = (col >> 3) ^ (row & 7);
                    reinterpret_cast<u16*>(reinterpret_cast<char*>(SH)
                        + row*512 + ch*16)[col & 7] = f2bf(acc[i][j][r] * fac);
                }
        __syncthreads();
        u16* dst = (z == 0) ? qh : (z == 1) ? kh : vh;
        #pragma unroll
        for (int p = 0; p < 16; ++p) {
            const int id  = p*256 + tid;
            const int row = id >> 5;
            const int c16 = id & 31;
            const int ch  = c16 ^ (row & 7);
            uint4 v = *reinterpret_cast<const uint4*>(
                reinterpret_cast<char*>(SH) + row*512 + ch*16);
            const int m = mBase + row;
            const int s = m >> 3, bb = m & 7;
            const int n = nBase + c16*8;
            const int h = (n >> 6) & 15;
            *reinterpret_cast<uint4*>(dst + ((size_t)(bb*NH + h)*SEQ + s)*DH + (n & 63)) = v;
        }
    } else {
        #pragma unroll
        for (int i = 0; i < 4; ++i)
            #pragma unroll
            for (int j = 0; j < 8; ++j)
                #pragma unroll
                for (int r = 0; r < 4; ++r) {
                    const int m = mBase + wm*64 + i*16 + rbase + r;
                    const int n = nBase + wn*128 + j*16 + l15;
                    outp[(size_t)m*1024 + n] = acc[i][j][r] + bias[n];
                }
    }
}

// ------- transpose V + residual (residual from xb, bf16), KEY-PERMUTED for b128 PV reads --------
__global__ __launch_bounds__(256) void vtrans_k(const u16* __restrict__ vh,
                                                const u16* __restrict__ xb,
                                                u16* __restrict__ vt) {
    __shared__ u16 T[64*64];
    const int tid = threadIdx.x;
    const int s0 = blockIdx.x * 64;
    const int bh = blockIdx.y;
    const int b  = bh >> 4;
    const int h  = bh & 15;
    const size_t base = (size_t)bh * (SEQ*DH);
    #pragma unroll
    for (int k = 0; k < 2; ++k) {
        const int idx = k*256 + tid;
        const int r = idx >> 3, c = idx & 7;
        union { uint4 v; u16 u[8]; } val;
        val.v = *reinterpret_cast<const uint4*>(vh + base + (size_t)(s0 + r)*DH + c*8);
        union { uint4 v; u16 u[8]; } xv;
        xv.v = *reinterpret_cast<const uint4*>(
            xb + ((size_t)(s0 + r)*BSZ + b)*EMB + h*DH + c*8);
        #pragma unroll
        for (int i = 0; i < 8; ++i)
            val.u[i] = f2bf(bf2f(val.u[i]) + bf2f(xv.u[i]));
        const int cs = c ^ (r & 7) ^ ((r >> 3) & 7);
        *reinterpret_cast<uint4*>(reinterpret_cast<char*>(T) + r*128 + cs*16) = val.v;
    }
    __syncthreads();
    #pragma unroll
    for (int k = 0; k < 2; ++k) {
        const int idx = k*256 + tid;
        const int d = idx >> 3, kc = idx & 7;
        union { u16 u[8]; uint2 w[2]; } o;
        #pragma unroll
        for (int i = 0; i < 8; ++i) {
            const int s = kc*8 + i;
            const int ch = (d >> 3) ^ (s & 7) ^ ((s >> 3) & 7);
            o.u[i] = T[s*64 + ch*8 + (d & 7)];
        }
        const int blk = (kc >> 2) * 32;
        const int hbit = (kc >> 1) & 1;
        const int g20 = (2*kc) & 3;
        const int g21 = (2*kc + 1) & 3;
        u16* basep = vt + base + (size_t)d*SEQ + s0 + blk + 4*hbit;
        *reinterpret_cast<uint2*>(basep + 8*g20) = o.w[0];
        *reinterpret_cast<uint2*>(basep + 8*g21) = o.w[1];
    }
}

// ---------------- flash attention: swapped QK^T, in-register softmax (R9 proven) ----------------
// ST = mfma(K, Q): lane owns 16-key slices of ONE q-row. PV uses k-slot perm
// pi(lg,e)=16(e>>2)+4lg+(e&3) on both P (in-lane pack order) and V (pre-permuted
// in vt by vtrans_k) -> V fragments are single b128 reads at the K-read offsets.
__global__ __launch_bounds__(256, 4) void attn_k(
    const u16* __restrict__ qh, const u16* __restrict__ kh,
    const u16* __restrict__ vt, const float* __restrict__ mask,
    u16* __restrict__ ctx)
{
    __shared__ u16 Kl[2][KVB*64];   // [key][d], 16B chunks ^ (key&7)
    __shared__ u16 Vl[2][KVB*64];   // [d][permuted key], 16B chunks ^ (d&7)

    const int tid  = threadIdx.x;
    const int lane = tid & 63;
    const int wv   = tid >> 6;
    const int l15  = lane & 15;
    const int lg   = lane >> 4;

    const int d0 = blockIdx.y * 8 + blockIdx.x;
    const int bh = (d0 & 7) * 16 + (d0 >> 6);
    const int qt = (d0 >> 3) & 7;
    const int b  = bh >> 4;
    const int h  = bh & 15;
    const int qbase = qt * 128;
    const size_t bhOff = (size_t)bh * (SEQ*DH);

    const int rS = tid >> 3;
    const int cS = (tid & 7) ^ (rS & 7);
    const u16* kSrc = kh + bhOff + (size_t)rS*DH  + cS*8;
    const u16* vSrc = vt + bhOff + (size_t)rS*SEQ + cS*8;
    const int ldst = wv * 512;

    bf16x8 aq[2][2];
    #pragma unroll
    for (int fq = 0; fq < 2; ++fq)
        #pragma unroll
        for (int kk = 0; kk < 2; ++kk)
            aq[fq][kk] = *reinterpret_cast<const bf16x8*>(
                qh + bhOff + (size_t)(qbase + wv*32 + fq*16 + l15)*DH + kk*32 + lg*8);

    f32x4 o[2][4];
    float mrun[2], lrun[2];
    #pragma unroll
    for (int fq = 0; fq < 2; ++fq) {
        #pragma unroll
        for (int fd = 0; fd < 4; ++fd) o[fq][fd] = (f32x4){0.f,0.f,0.f,0.f};
        mrun[fq] = -1e30f; lrun[fq] = 0.f;
    }

    const int co0 = ((lg)     ^ (l15 & 7)) << 4;
    const int co1 = ((4 + lg) ^ (l15 & 7)) << 4;
    const float* mPtrT = mask + (size_t)b*SEQ + lg*4;

    auto stage = [&](int buf, int kt) {
        const int jb = kt * KVB;
        GLDS16(kSrc + (size_t)jb*DH,        &Kl[buf][ldst]);
        GLDS16(kSrc + (size_t)(jb+32)*DH,   &Kl[buf][2048 + ldst]);
        GLDS16(vSrc + jb,                   &Vl[buf][ldst]);
        GLDS16(vSrc + 32*SEQ + jb,          &Vl[buf][2048 + ldst]);
    };

    stage(0, 0);
    int cur = 0;

    for (int kt = 0; kt < 16; ++kt) {
        __syncthreads();
        if (kt + 1 < 16) stage(cur ^ 1, kt + 1);
        const int jb = kt * KVB;

        // ---- ST = K·Q^T ----
        f32x4 sc[2][4];
        const char* kb = reinterpret_cast<const char*>(&Kl[cur][0]) + l15*128;
        #pragma unroll
        for (int fn = 0; fn < 4; ++fn) {
            bf16x8 k0 = *reinterpret_cast<const bf16x8*>(kb + fn*2048 + co0);
            bf16x8 k1 = *reinterpret_cast<const bf16x8*>(kb + fn*2048 + co1);
            #pragma unroll
            for (int fq = 0; fq < 2; ++fq) {
                f32x4 t = __builtin_amdgcn_mfma_f32_16x16x32_bf16(k0, aq[fq][0],
                            (f32x4){0.f,0.f,0.f,0.f}, 0, 0, 0);
                sc[fq][fn] = __builtin_amdgcn_mfma_f32_16x16x32_bf16(k1, aq[fq][1], t, 0, 0, 0);
            }
        }
        // ---- mask (log2 domain) ----
        #pragma unroll
        for (int fn = 0; fn < 4; ++fn) {
            float4 mk = *reinterpret_cast<const float4*>(mPtrT + jb + fn*16);
            const float mkf[4] = {mk.x, mk.y, mk.z, mk.w};
            #pragma unroll
            for (int fq = 0; fq < 2; ++fq)
                #pragma unroll
                for (int r = 0; r < 4; ++r)
                    sc[fq][fn][r] = fmaf(mkf[r], L2E, sc[fq][fn][r]);
        }
        // ---- max ----
        float mx[2];
        #pragma unroll
        for (int fq = 0; fq < 2; ++fq) {
            float m01 = fmaxf(fmaxf(sc[fq][0][0], sc[fq][0][1]),
                              fmaxf(sc[fq][0][2], sc[fq][0][3]));
            #pragma unroll
            for (int fn = 1; fn < 4; ++fn)
                m01 = fmaxf(m01, fmaxf(fmaxf(sc[fq][fn][0], sc[fq][fn][1]),
                                       fmaxf(sc[fq][fn][2], sc[fq][fn][3])));
            m01 = fmaxf(m01, __shfl_xor(m01, 16));
            m01 = fmaxf(m01, __shfl_xor(m01, 32));
            mx[fq] = m01;
        }
        // ---- defer-max rescale ----
        int need = (mx[0] > mrun[0] + 11.5f) | (mx[1] > mrun[1] + 11.5f);
        if (__any(need)) {
            #pragma unroll
            for (int fq = 0; fq < 2; ++fq) {
                const float mn  = fmaxf(mrun[fq], mx[fq]);
                const float scl = fexp2(mrun[fq] - mn);
                mrun[fq] = mn;
                lrun[fq] *= scl;
                float s4[4];
                #pragma unroll
                for (int r = 0; r < 4; ++r) s4[r] = __shfl(scl, lg*4 + r);
                #pragma unroll
                for (int fd = 0; fd < 4; ++fd)
                    #pragma unroll
                    for (int r = 0; r < 4; ++r) o[fq][fd][r] *= s4[r];
            }
        }
        // ---- P = exp2(sc - m), pack (A-frag under pi), row-sum ----
        u32 pw[2][2][4];
        #pragma unroll
        for (int fq = 0; fq < 2; ++fq) {
            float rs = 0.f;
            #pragma unroll
            for (int fn = 0; fn < 4; ++fn) {
                const float p0 = fexp2(sc[fq][fn][0] - mrun[fq]);
                const float p1 = fexp2(sc[fq][fn][1] - mrun[fq]);
                const float p2 = fexp2(sc[fq][fn][2] - mrun[fq]);
                const float p3 = fexp2(sc[fq][fn][3] - mrun[fq]);
                rs += (p0 + p1) + (p2 + p3);
                u32 wA, wB;
                asm("v_cvt_pk_bf16_f32 %0, %1, %2" : "=v"(wA) : "v"(p0), "v"(p1));
                asm("v_cvt_pk_bf16_f32 %0, %1, %2" : "=v"(wB) : "v"(p2), "v"(p3));
                pw[fq][fn >> 1][(fn & 1)*2 + 0] = wA;
                pw[fq][fn >> 1][(fn & 1)*2 + 1] = wB;
            }
            rs += __shfl_xor(rs, 16);
            rs += __shfl_xor(rs, 32);
            lrun[fq] += rs;
        }
        bf16x8 pa[2][2];
        #pragma unroll
        for (int fq = 0; fq < 2; ++fq)
            #pragma unroll
            for (int kk = 0; kk < 2; ++kk) {
                union { u32 w[4]; bf16x8 v; } u;
                u.w[0] = pw[fq][kk][0]; u.w[1] = pw[fq][kk][1];
                u.w[2] = pw[fq][kk][2]; u.w[3] = pw[fq][kk][3];
                pa[fq][kk] = u.v;
            }
        // ---- O += P·V : V pre-permuted -> b128 reads at K-read offsets ----
        const char* vb = reinterpret_cast<const char*>(&Vl[cur][0]) + l15*128;
        #pragma unroll
        for (int kk = 0; kk < 2; ++kk) {
            const int coff = kk ? co1 : co0;
            #pragma unroll
            for (int fd = 0; fd < 4; ++fd) {
                bf16x8 vf = *reinterpret_cast<const bf16x8*>(vb + fd*2048 + coff);
                #pragma unroll
                for (int fq = 0; fq < 2; ++fq)
                    o[fq][fd] = __builtin_amdgcn_mfma_f32_16x16x32_bf16(pa[fq][kk], vf, o[fq][fd], 0, 0, 0);
            }
        }
        cur ^= 1;
    }

    #pragma unroll
    for (int fq = 0; fq < 2; ++fq) {
        const float linv = 1.0f / lrun[fq];
        float inv4[4];
        #pragma unroll
        for (int r = 0; r < 4; ++r) inv4[r] = __shfl(linv, lg*4 + r);
        #pragma unroll
        for (int r = 0; r < 4; ++r) {
            const int s = qbase + wv*32 + fq*16 + lg*4 + r;
            #pragma unroll
            for (int fd = 0; fd < 4; ++fd) {
                const int d = fd*16 + l15;
                ctx[((size_t)(s*BSZ + b))*EMB + h*DH + d] = f2bf(o[fq][fd][r] * inv4[r]);
            }
        }
    }
}

extern "C" void kernel_launch(void* const* d_in, const int* in_sizes, int n_in,
                              void* d_out, int out_size, void* d_ws, size_t ws_size,
                              hipStream_t stream) {
    const float* x    = (const float*)d_in[0];
    const float* mask = (const float*)d_in[1];
    const float* w_q  = (const float*)d_in[2];
    const float* w_k  = (const float*)d_in[3];
    const float* w_v  = (const float*)d_in[4];
    const float* w_o  = (const float*)d_in[5];
    const float* b_o  = (const float*)d_in[6];

    char* ws = (char*)d_ws;
    u16* xb  = (u16*)(ws);                        // 16 MB
    u16* wT  = (u16*)(ws + ((size_t)16 << 20));   // 8 MB
    u16* qh  = (u16*)(ws + ((size_t)24 << 20));   // 16 MB
    u16* kh  = (u16*)(ws + ((size_t)40 << 20));   // 16 MB
    u16* vt  = (u16*)(ws + ((size_t)56 << 20));   // 16 MB (V transposed + key-permuted)
    u16* vh  = (u16*)(ws + ((size_t)72 << 20));   // 16 MB
    u16* ctx = vh;                                // vh dead after vtrans
    float* outp = (float*)d_out;

    cvt_k<<<6144, 256, 0, stream>>>(x, w_q, w_k, w_v, w_o, xb, wT);
    gemm_t<0><<<768, 256, 0, stream>>>(xb, wT, nullptr, qh, kh, vh, nullptr);
    vtrans_k<<<dim3(16, 128), 256, 0, stream>>>(vh, xb, vt);
    attn_k<<<dim3(8, 128), 256, 0, stream>>>(qh, kh, vt, mask, ctx);
    gemm_t<1><<<256, 256, 0, stream>>>(ctx, wT + (size_t)3*1048576, b_o,
                                       nullptr, nullptr, nullptr, outp);
}

// Round 16
// 170.183 us; speedup vs baseline: 1.2286x; 1.0221x over previous
//
#include <hip/hip_runtime.h>

typedef unsigned short u16;
typedef unsigned int   u32;
typedef __attribute__((ext_vector_type(8))) short bf16x8;
typedef __attribute__((ext_vector_type(4))) float f32x4;

#define SEQ 1024
#define BSZ 8
#define EMB 1024
#define NH  16
#define DH  64
#define KVB 64
#define L2E 1.44269504088896f

__device__ __forceinline__ u16 f2bf(float f) {
    u32 u = __float_as_uint(f);
    u32 r = u + 0x7FFFu + ((u >> 16) & 1u);   // round-to-nearest-even
    return (u16)(r >> 16);
}
__device__ __forceinline__ float bf2f(u16 u) {
    return __uint_as_float((u32)u << 16);
}
__device__ __forceinline__ float fexp2(float x) {
    return __builtin_amdgcn_exp2f(x);
}

#define GLDS16(g, l) __builtin_amdgcn_global_load_lds( \
    (const __attribute__((address_space(1))) void*)(g), \
    (__attribute__((address_space(3))) void*)(l), 16, 0, 0)

// ------- merged convert: x (fp32)->xb (bf16); w (K,N) fp32 -> wT (N,K) bf16 -------
__global__ __launch_bounds__(256) void cvt_k(
    const float* __restrict__ x, const float* __restrict__ w0,
    const float* __restrict__ w1, const float* __restrict__ w2,
    const float* __restrict__ w3, u16* __restrict__ xb, u16* __restrict__ wT)
{
    const int bid = blockIdx.x;
    if (bid < 4096) {
        size_t i = ((size_t)bid * 256 + threadIdx.x) * 8;
        float4 a = *reinterpret_cast<const float4*>(x + i);
        float4 b = *reinterpret_cast<const float4*>(x + i + 4);
        union { u16 u[8]; uint4 v; } o;
        o.u[0]=f2bf(a.x); o.u[1]=f2bf(a.y); o.u[2]=f2bf(a.z); o.u[3]=f2bf(a.w);
        o.u[4]=f2bf(b.x); o.u[5]=f2bf(b.y); o.u[6]=f2bf(b.z); o.u[7]=f2bf(b.w);
        *reinterpret_cast<uint4*>(xb + i) = o.v;
    } else {
        int id  = (bid - 4096) * 256 + threadIdx.x;
        int wi  = id >> 17;
        int rem = id & 131071;
        int kc  = rem >> 10;
        int n   = rem & 1023;
        const float* src = (wi==0) ? w0 : (wi==1) ? w1 : (wi==2) ? w2 : w3;
        union { u16 u[8]; uint4 v; } o;
        #pragma unroll
        for (int i = 0; i < 8; ++i) o.u[i] = f2bf(src[(size_t)(kc*8+i)*1024 + n]);
        *reinterpret_cast<uint4*>(wT + (size_t)wi*1048576 + (size_t)n*1024 + kc*8) = o.v;
    }
}

// ---------------- GEMM: BM=128 x BN=256, 4 waves (2Mx2N), wave=64x128 ----------------
// 3 LDS buffers (72KB) -> 2 WGs/CU; counted vmcnt(6), 1 barrier/iter.
template<int MODE>
__global__ __launch_bounds__(256, 2) void gemm_t(
    const u16* __restrict__ A, const u16* __restrict__ BT,
    const float* __restrict__ bias,
    u16* __restrict__ qh, u16* __restrict__ kh, u16* __restrict__ vh,
    float* __restrict__ outp)
{
    __shared__ u16 SH[36864];                 // 72KB
    u16* Asb = SH;
    u16* Bsb = SH + 12288;

    const int tid  = threadIdx.x;
    const int lane = tid & 63;
    const int wv   = tid >> 6;
    const int wm   = wv >> 1;
    const int wn   = wv & 1;
    const int l15  = lane & 15;
    const int lg   = lane >> 4;

    const int nwg  = gridDim.x;
    const int flat = blockIdx.x;
    const int rid  = (flat & 7) * (nwg >> 3) + (flat >> 3);
    const int NB   = (MODE == 0) ? 12 : 4;
    const int mBlk = rid / NB;
    const int nb   = rid - mBlk * NB;
    const int mBase = mBlk * 128;
    const int nBase = nb * 256;

    const int rS = tid >> 2;
    const int cS = (tid & 3) ^ ((rS >> 1) & 3);
    const u16* aSrc = A  + (size_t)(mBase + rS) * 1024 + cS*8;
    const u16* bSrc = BT + (size_t)(nBase + rS) * 1024 + cS*8;
    const int wb = wv * 512;

    f32x4 acc[4][8];
    #pragma unroll
    for (int i = 0; i < 4; ++i)
        #pragma unroll
        for (int j = 0; j < 8; ++j) acc[i][j] = (f32x4){0.f,0.f,0.f,0.f};

    const int arow = wm*64  + l15;
    const int brow = wn*128 + l15;
    const int aoff = arow*64 + ((lg ^ ((arow >> 1) & 3)) << 4);
    const int boff = brow*64 + ((lg ^ ((brow >> 1) & 3)) << 4);

    auto stg = [&](int buf, int kt) {
        const int ko = kt * 32;
        GLDS16(aSrc + ko,                    &Asb[buf*4096 + wb]);
        GLDS16(aSrc + (size_t)64*1024 + ko,  &Asb[buf*4096 + 2048 + wb]);
        GLDS16(bSrc + ko,                    &Bsb[buf*8192 + wb]);
        GLDS16(bSrc + (size_t)64*1024 + ko,  &Bsb[buf*8192 + 2048 + wb]);
        GLDS16(bSrc + (size_t)128*1024 + ko, &Bsb[buf*8192 + 4096 + wb]);
        GLDS16(bSrc + (size_t)192*1024 + ko, &Bsb[buf*8192 + 6144 + wb]);
    };

    const int NT = 32;
    stg(0, 0);
    stg(1, 1);
    int cur = 0, nxt = 2;
    for (int kt = 0; kt < NT; ++kt) {
        if (kt < NT - 1) asm volatile("s_waitcnt vmcnt(6)" ::: "memory");
        else             asm volatile("s_waitcnt vmcnt(0)" ::: "memory");
        __builtin_amdgcn_s_barrier();
        bf16x8 af[4], bf[8];
        #pragma unroll
        for (int i = 0; i < 4; ++i)
            af[i] = *reinterpret_cast<const bf16x8*>(
                reinterpret_cast<const char*>(&Asb[cur*4096]) + aoff + i*1024);
        #pragma unroll
        for (int j = 0; j < 8; ++j)
            bf[j] = *reinterpret_cast<const bf16x8*>(
                reinterpret_cast<const char*>(&Bsb[cur*8192]) + boff + j*1024);
        if (kt + 2 < NT) stg(nxt, kt + 2);
        asm volatile("s_waitcnt lgkmcnt(0)" ::: "memory");
        __builtin_amdgcn_sched_barrier(0);
        __builtin_amdgcn_s_setprio(1);
        #pragma unroll
        for (int i = 0; i < 4; ++i)
            #pragma unroll
            for (int j = 0; j < 8; ++j)
                acc[i][j] = __builtin_amdgcn_mfma_f32_16x16x32_bf16(af[i], bf[j], acc[i][j], 0, 0, 0);
        __builtin_amdgcn_s_setprio(0);
        cur = (cur == 2) ? 0 : cur + 1;
        nxt = (nxt == 2) ? 0 : nxt + 1;
    }

    const int rbase = lg * 4;

    if (MODE == 0) {
        __syncthreads();
        const int z = nBase >> 10;
        const float fac = (z == 0) ? 0.125f * L2E : 1.0f;
        #pragma unroll
        for (int i = 0; i < 4; ++i)
            #pragma unroll
            for (int j = 0; j < 8; ++j)
                #pragma unroll
                for (int r = 0; r < 4; ++r) {
                    const int row = wm*64 + i*16 + rbase + r;
                    const int col = wn*128 + j*16 + l15;
                    const int ch  = (col >> 3) ^ (row & 7);
                    reinterpret_cast<u16*>(reinterpret_cast<char*>(SH)
                        + row*512 + ch*16)[col & 7] = f2bf(acc[i][j][r] * fac);
                }
        __syncthreads();
        u16* dst = (z == 0) ? qh : (z == 1) ? kh : vh;
        #pragma unroll
        for (int p = 0; p < 16; ++p) {
            const int id  = p*256 + tid;
            const int row = id >> 5;
            const int c16 = id & 31;
            const int ch  = c16 ^ (row & 7);
            uint4 v = *reinterpret_cast<const uint4*>(
                reinterpret_cast<char*>(SH) + row*512 + ch*16);
            const int m = mBase + row;
            const int s = m >> 3, bb = m & 7;
            const int n = nBase + c16*8;
            const int h = (n >> 6) & 15;
            *reinterpret_cast<uint4*>(dst + ((size_t)(bb*NH + h)*SEQ + s)*DH + (n & 63)) = v;
        }
    } else {
        #pragma unroll
        for (int i = 0; i < 4; ++i)
            #pragma unroll
            for (int j = 0; j < 8; ++j)
                #pragma unroll
                for (int r = 0; r < 4; ++r) {
                    const int m = mBase + wm*64 + i*16 + rbase + r;
                    const int n = nBase + wn*128 + j*16 + l15;
                    outp[(size_t)m*1024 + n] = acc[i][j][r] + bias[n];
                }
    }
}

// ------- transpose V + residual (residual from xb, bf16), KEY-PERMUTED for b128 PV reads --------
__global__ __launch_bounds__(256) void vtrans_k(const u16* __restrict__ vh,
                                                const u16* __restrict__ xb,
                                                u16* __restrict__ vt) {
    __shared__ u16 T[64*64];
    const int tid = threadIdx.x;
    const int s0 = blockIdx.x * 64;
    const int bh = blockIdx.y;
    const int b  = bh >> 4;
    const int h  = bh & 15;
    const size_t base = (size_t)bh * (SEQ*DH);
    #pragma unroll
    for (int k = 0; k < 2; ++k) {
        const int idx = k*256 + tid;
        const int r = idx >> 3, c = idx & 7;
        union { uint4 v; u16 u[8]; } val;
        val.v = *reinterpret_cast<const uint4*>(vh + base + (size_t)(s0 + r)*DH + c*8);
        union { uint4 v; u16 u[8]; } xv;
        xv.v = *reinterpret_cast<const uint4*>(
            xb + ((size_t)(s0 + r)*BSZ + b)*EMB + h*DH + c*8);
        #pragma unroll
        for (int i = 0; i < 8; ++i)
            val.u[i] = f2bf(bf2f(val.u[i]) + bf2f(xv.u[i]));
        const int cs = c ^ (r & 7) ^ ((r >> 3) & 7);
        *reinterpret_cast<uint4*>(reinterpret_cast<char*>(T) + r*128 + cs*16) = val.v;
    }
    __syncthreads();
    #pragma unroll
    for (int k = 0; k < 2; ++k) {
        const int idx = k*256 + tid;
        const int d = idx >> 3, kc = idx & 7;
        union { u16 u[8]; uint2 w[2]; } o;
        #pragma unroll
        for (int i = 0; i < 8; ++i) {
            const int s = kc*8 + i;
            const int ch = (d >> 3) ^ (s & 7) ^ ((s >> 3) & 7);
            o.u[i] = T[s*64 + ch*8 + (d & 7)];
        }
        const int blk = (kc >> 2) * 32;
        const int hbit = (kc >> 1) & 1;
        const int g20 = (2*kc) & 3;
        const int g21 = (2*kc + 1) & 3;
        u16* basep = vt + base + (size_t)d*SEQ + s0 + blk + 4*hbit;
        *reinterpret_cast<uint2*>(basep + 8*g20) = o.w[0];
        *reinterpret_cast<uint2*>(basep + 8*g21) = o.w[1];
    }
}

// ---------------- flash attention: swapped QK^T, in-register softmax (R14 proven) ----------------
// + T5: s_setprio around the QK and PV MFMA clusters (attn-positive per m191).
__global__ __launch_bounds__(256, 4) void attn_k(
    const u16* __restrict__ qh, const u16* __restrict__ kh,
    const u16* __restrict__ vt, const float* __restrict__ mask,
    u16* __restrict__ ctx)
{
    __shared__ u16 Kl[2][KVB*64];   // [key][d], 16B chunks ^ (key&7)
    __shared__ u16 Vl[2][KVB*64];   // [d][permuted key], 16B chunks ^ (d&7)

    const int tid  = threadIdx.x;
    const int lane = tid & 63;
    const int wv   = tid >> 6;
    const int l15  = lane & 15;
    const int lg   = lane >> 4;

    const int d0 = blockIdx.y * 8 + blockIdx.x;
    const int bh = (d0 & 7) * 16 + (d0 >> 6);
    const int qt = (d0 >> 3) & 7;
    const int b  = bh >> 4;
    const int h  = bh & 15;
    const int qbase = qt * 128;
    const size_t bhOff = (size_t)bh * (SEQ*DH);

    const int rS = tid >> 3;
    const int cS = (tid & 7) ^ (rS & 7);
    const u16* kSrc = kh + bhOff + (size_t)rS*DH  + cS*8;
    const u16* vSrc = vt + bhOff + (size_t)rS*SEQ + cS*8;
    const int ldst = wv * 512;

    bf16x8 aq[2][2];
    #pragma unroll
    for (int fq = 0; fq < 2; ++fq)
        #pragma unroll
        for (int kk = 0; kk < 2; ++kk)
            aq[fq][kk] = *reinterpret_cast<const bf16x8*>(
                qh + bhOff + (size_t)(qbase + wv*32 + fq*16 + l15)*DH + kk*32 + lg*8);

    f32x4 o[2][4];
    float mrun[2], lrun[2];
    #pragma unroll
    for (int fq = 0; fq < 2; ++fq) {
        #pragma unroll
        for (int fd = 0; fd < 4; ++fd) o[fq][fd] = (f32x4){0.f,0.f,0.f,0.f};
        mrun[fq] = -1e30f; lrun[fq] = 0.f;
    }

    const int co0 = ((lg)     ^ (l15 & 7)) << 4;
    const int co1 = ((4 + lg) ^ (l15 & 7)) << 4;
    const float* mPtrT = mask + (size_t)b*SEQ + lg*4;

    auto stage = [&](int buf, int kt) {
        const int jb = kt * KVB;
        GLDS16(kSrc + (size_t)jb*DH,        &Kl[buf][ldst]);
        GLDS16(kSrc + (size_t)(jb+32)*DH,   &Kl[buf][2048 + ldst]);
        GLDS16(vSrc + jb,                   &Vl[buf][ldst]);
        GLDS16(vSrc + 32*SEQ + jb,          &Vl[buf][2048 + ldst]);
    };

    stage(0, 0);
    int cur = 0;

    for (int kt = 0; kt < 16; ++kt) {
        __syncthreads();
        if (kt + 1 < 16) stage(cur ^ 1, kt + 1);
        const int jb = kt * KVB;

        // ---- ST = K·Q^T ----
        f32x4 sc[2][4];
        const char* kb = reinterpret_cast<const char*>(&Kl[cur][0]) + l15*128;
        __builtin_amdgcn_s_setprio(1);
        #pragma unroll
        for (int fn = 0; fn < 4; ++fn) {
            bf16x8 k0 = *reinterpret_cast<const bf16x8*>(kb + fn*2048 + co0);
            bf16x8 k1 = *reinterpret_cast<const bf16x8*>(kb + fn*2048 + co1);
            #pragma unroll
            for (int fq = 0; fq < 2; ++fq) {
                f32x4 t = __builtin_amdgcn_mfma_f32_16x16x32_bf16(k0, aq[fq][0],
                            (f32x4){0.f,0.f,0.f,0.f}, 0, 0, 0);
                sc[fq][fn] = __builtin_amdgcn_mfma_f32_16x16x32_bf16(k1, aq[fq][1], t, 0, 0, 0);
            }
        }
        __builtin_amdgcn_s_setprio(0);
        // ---- mask (log2 domain) ----
        #pragma unroll
        for (int fn = 0; fn < 4; ++fn) {
            float4 mk = *reinterpret_cast<const float4*>(mPtrT + jb + fn*16);
            const float mkf[4] = {mk.x, mk.y, mk.z, mk.w};
            #pragma unroll
            for (int fq = 0; fq < 2; ++fq)
                #pragma unroll
                for (int r = 0; r < 4; ++r)
                    sc[fq][fn][r] = fmaf(mkf[r], L2E, sc[fq][fn][r]);
        }
        // ---- max ----
        float mx[2];
        #pragma unroll
        for (int fq = 0; fq < 2; ++fq) {
            float m01 = fmaxf(fmaxf(sc[fq][0][0], sc[fq][0][1]),
                              fmaxf(sc[fq][0][2], sc[fq][0][3]));
            #pragma unroll
            for (int fn = 1; fn < 4; ++fn)
                m01 = fmaxf(m01, fmaxf(fmaxf(sc[fq][fn][0], sc[fq][fn][1]),
                                       fmaxf(sc[fq][fn][2], sc[fq][fn][3])));
            m01 = fmaxf(m01, __shfl_xor(m01, 16));
            m01 = fmaxf(m01, __shfl_xor(m01, 32));
            mx[fq] = m01;
        }
        // ---- defer-max rescale ----
        int need = (mx[0] > mrun[0] + 11.5f) | (mx[1] > mrun[1] + 11.5f);
        if (__any(need)) {
            #pragma unroll
            for (int fq = 0; fq < 2; ++fq) {
                const float mn  = fmaxf(mrun[fq], mx[fq]);
                const float scl = fexp2(mrun[fq] - mn);
                mrun[fq] = mn;
                lrun[fq] *= scl;
                float s4[4];
                #pragma unroll
                for (int r = 0; r < 4; ++r) s4[r] = __shfl(scl, lg*4 + r);
                #pragma unroll
                for (int fd = 0; fd < 4; ++fd)
                    #pragma unroll
                    for (int r = 0; r < 4; ++r) o[fq][fd][r] *= s4[r];
            }
        }
        // ---- P = exp2(sc - m), pack (A-frag under pi), row-sum ----
        u32 pw[2][2][4];
        #pragma unroll
        for (int fq = 0; fq < 2; ++fq) {
            float rs = 0.f;
            #pragma unroll
            for (int fn = 0; fn < 4; ++fn) {
                const float p0 = fexp2(sc[fq][fn][0] - mrun[fq]);
                const float p1 = fexp2(sc[fq][fn][1] - mrun[fq]);
                const float p2 = fexp2(sc[fq][fn][2] - mrun[fq]);
                const float p3 = fexp2(sc[fq][fn][3] - mrun[fq]);
                rs += (p0 + p1) + (p2 + p3);
                u32 wA, wB;
                asm("v_cvt_pk_bf16_f32 %0, %1, %2" : "=v"(wA) : "v"(p0), "v"(p1));
                asm("v_cvt_pk_bf16_f32 %0, %1, %2" : "=v"(wB) : "v"(p2), "v"(p3));
                pw[fq][fn >> 1][(fn & 1)*2 + 0] = wA;
                pw[fq][fn >> 1][(fn & 1)*2 + 1] = wB;
            }
            rs += __shfl_xor(rs, 16);
            rs += __shfl_xor(rs, 32);
            lrun[fq] += rs;
        }
        bf16x8 pa[2][2];
        #pragma unroll
        for (int fq = 0; fq < 2; ++fq)
            #pragma unroll
            for (int kk = 0; kk < 2; ++kk) {
                union { u32 w[4]; bf16x8 v; } u;
                u.w[0] = pw[fq][kk][0]; u.w[1] = pw[fq][kk][1];
                u.w[2] = pw[fq][kk][2]; u.w[3] = pw[fq][kk][3];
                pa[fq][kk] = u.v;
            }
        // ---- O += P·V : V pre-permuted -> b128 reads at K-read offsets ----
        const char* vb = reinterpret_cast<const char*>(&Vl[cur][0]) + l15*128;
        __builtin_amdgcn_s_setprio(1);
        #pragma unroll
        for (int kk = 0; kk < 2; ++kk) {
            const int coff = kk ? co1 : co0;
            #pragma unroll
            for (int fd = 0; fd < 4; ++fd) {
                bf16x8 vf = *reinterpret_cast<const bf16x8*>(vb + fd*2048 + coff);
                #pragma unroll
                for (int fq = 0; fq < 2; ++fq)
                    o[fq][fd] = __builtin_amdgcn_mfma_f32_16x16x32_bf16(pa[fq][kk], vf, o[fq][fd], 0, 0, 0);
            }
        }
        __builtin_amdgcn_s_setprio(0);
        cur ^= 1;
    }

    #pragma unroll
    for (int fq = 0; fq < 2; ++fq) {
        const float linv = 1.0f / lrun[fq];
        float inv4[4];
        #pragma unroll
        for (int r = 0; r < 4; ++r) inv4[r] = __shfl(linv, lg*4 + r);
        #pragma unroll
        for (int r = 0; r < 4; ++r) {
            const int s = qbase + wv*32 + fq*16 + lg*4 + r;
            #pragma unroll
            for (int fd = 0; fd < 4; ++fd) {
                const int d = fd*16 + l15;
                ctx[((size_t)(s*BSZ + b))*EMB + h*DH + d] = f2bf(o[fq][fd][r] * inv4[r]);
            }
        }
    }
}

extern "C" void kernel_launch(void* const* d_in, const int* in_sizes, int n_in,
                              void* d_out, int out_size, void* d_ws, size_t ws_size,
                              hipStream_t stream) {
    const float* x    = (const float*)d_in[0];
    const float* mask = (const float*)d_in[1];
    const float* w_q  = (const float*)d_in[2];
    const float* w_k  = (const float*)d_in[3];
    const float* w_v  = (const float*)d_in[4];
    const float* w_o  = (const float*)d_in[5];
    const float* b_o  = (const float*)d_in[6];

    char* ws = (char*)d_ws;
    u16* xb  = (u16*)(ws);                        // 16 MB
    u16* wT  = (u16*)(ws + ((size_t)16 << 20));   // 8 MB
    u16* qh  = (u16*)(ws + ((size_t)24 << 20));   // 16 MB
    u16* kh  = (u16*)(ws + ((size_t)40 << 20));   // 16 MB
    u16* vt  = (u16*)(ws + ((size_t)56 << 20));   // 16 MB (V transposed + key-permuted)
    u16* vh  = (u16*)(ws + ((size_t)72 << 20));   // 16 MB
    u16* ctx = vh;                                // vh dead after vtrans
    float* outp = (float*)d_out;

    cvt_k<<<6144, 256, 0, stream>>>(x, w_q, w_k, w_v, w_o, xb, wT);
    gemm_t<0><<<768, 256, 0, stream>>>(xb, wT, nullptr, qh, kh, vh, nullptr);
    vtrans_k<<<dim3(16, 128), 256, 0, stream>>>(vh, xb, vt);
    attn_k<<<dim3(8, 128), 256, 0, stream>>>(qh, kh, vt, mask, ctx);
    gemm_t<1><<<256, 256, 0, stream>>>(ctx, wT + (size_t)3*1048576, b_o,
                                       nullptr, nullptr, nullptr, outp);
}